// Round 9
// baseline (1091.589 us; speedup 1.0000x reference)
//
#include <hip/hip_runtime.h>
#include <hip/hip_fp16.h>
#include <hip/hip_bf16.h>
#include <math.h>

// GAT 2-layer forward, MI355X. FP32 in/out, int32 edge_index.
// R21: CSR elimination. k_build/k_agg1f/k_agg2 replaced by edge-centric
// bucket kernels with LDS-atomic accumulators:
//   k_init  : cursor=0, wtg B-tile (unchanged R19)
//   k_pre   : scatter(CHK=4096) || gemm1 MFMA (unchanged R19)
//   k_agg1b : per 128-node half-bucket: compact staged edges -> stream
//             edges (16 lanes/edge), ds_add accS[128][64] + den; epilogue
//             adds self-loop, normalizes, ELU, fused gemm2 -> h2/a2.
//   k_agg2b : same for layer 2 (acc2S[128][17] padded) + log_softmax.
// 4 dispatches, no CSR build, no per-node gather chains.
// (R20 lesson: cooperative launch aborts harness graph capture - banned.)

#define BSH 8            // 256 nodes per bucket
#define BCAP 5120        // staged capacity per bucket
#define CHK 4096         // edges per scatter block
#define ELCAP 2816       // LDS edge-list capacity per half-bucket (+16 sigma)

typedef __attribute__((ext_vector_type(8))) short short8;
typedef __attribute__((ext_vector_type(8))) _Float16 half8;
typedef __attribute__((ext_vector_type(4))) float float4v;

static __device__ __forceinline__ short f2bf(float f) {
    __hip_bfloat16 b = __float2bfloat16(f);
    return *reinterpret_cast<short*>(&b);
}

// block 0: zero cursor. block 1: prep gemm1 B-tile (wtg[80*136] bf16).
__global__ __launch_bounds__(256) void k_init(int* __restrict__ cursor, int NBK,
                                              const float* __restrict__ W1,
                                              const float* __restrict__ att_src1,
                                              const float* __restrict__ att_dst1,
                                              short* __restrict__ wtg) {
    int tid = threadIdx.x;
    if (blockIdx.x == 0) {
        for (int i = tid; i < NBK; i += 256) cursor[i] = 0;
    } else {
        for (int i = tid; i < 128 * 64; i += 256) {
            int k = i >> 6, c = i & 63;
            wtg[c * 136 + k] = f2bf(W1[i]);
        }
        for (int i = tid; i < 16 * 128; i += 256) {
            int col = i >> 7, k = i & 127;
            float v = 0.f;
            if (col < 8) {
                int h = col & 3;
                const float* att = (col < 4) ? att_src1 : att_dst1;
                #pragma unroll
                for (int c = 0; c < 16; c++) v += W1[k * 64 + h * 16 + c] * att[h * 16 + c];
            }
            wtg[(64 + col) * 136 + k] = f2bf(v);
        }
    }
}

// Fused pass: blocks [0,GS) = edge scatter; blocks [GS,GS+GG) = gemm1.
__global__ __launch_bounds__(256) void k_pre(const int* __restrict__ ei, int* __restrict__ cursor,
                                             int* __restrict__ stage, int E, int NBK,
                                             const float* __restrict__ x,
                                             const short* __restrict__ wtg,
                                             __half* __restrict__ h1,
                                             float* __restrict__ a_src, float* __restrict__ a_dst,
                                             int N, int GS) {
    __shared__ __align__(16) char smem[80 * 136 * 2];
    int tid = threadIdx.x;
    if (blockIdx.x < GS) {
        int* hist = (int*)smem;
        int* cnt2 = hist + 512;
        int* base = cnt2 + 512;
        int e0 = blockIdx.x * CHK;
        int nedge = E - e0; if (nedge > CHK) nedge = CHK;
        int nv4 = nedge >> 2, rem = nedge & 3;
        const int4* dv4 = (const int4*)(ei + E + e0);
        const int4* sv4 = (const int4*)(ei + e0);
        for (int i = tid; i < 512; i += 256) { hist[i] = 0; cnt2[i] = 0; }
        __syncthreads();
        for (int i = tid; i < nv4; i += 256) {
            int4 d = dv4[i];
            atomicAdd(&hist[d.x >> BSH], 1);
            atomicAdd(&hist[d.y >> BSH], 1);
            atomicAdd(&hist[d.z >> BSH], 1);
            atomicAdd(&hist[d.w >> BSH], 1);
        }
        if (tid < rem) atomicAdd(&hist[ei[E + e0 + nv4 * 4 + tid] >> BSH], 1);
        __syncthreads();
        for (int b = tid; b < NBK; b += 256) {
            int c = hist[b];
            if (c > 0) base[b] = b * BCAP + atomicAdd(&cursor[b], c);
        }
        __syncthreads();
        for (int i = tid; i < nv4; i += 256) {
            int4 s = sv4[i];
            int4 d = dv4[i];
            int b, r;
            b = d.x >> BSH; r = atomicAdd(&cnt2[b], 1);
            stage[base[b] + r] = s.x | ((d.x & 255) << 17);
            b = d.y >> BSH; r = atomicAdd(&cnt2[b], 1);
            stage[base[b] + r] = s.y | ((d.y & 255) << 17);
            b = d.z >> BSH; r = atomicAdd(&cnt2[b], 1);
            stage[base[b] + r] = s.z | ((d.z & 255) << 17);
            b = d.w >> BSH; r = atomicAdd(&cnt2[b], 1);
            stage[base[b] + r] = s.w | ((d.w & 255) << 17);
        }
        if (tid < rem) {
            int e = nv4 * 4 + tid;
            int s = ei[e0 + e];
            int d = ei[E + e0 + e];
            int b = d >> BSH;
            int r = atomicAdd(&cnt2[b], 1);
            stage[base[b] + r] = s | ((d & 255) << 17);
        }
    } else {
        short* wt = (short*)smem;
        {
            int4* wd = (int4*)wt;
            const int4* ws = (const int4*)wtg;
            for (int i = tid; i < (80 * 136 * 2) / 16; i += 256) wd[i] = ws[i];
        }
        __syncthreads();
        int wave = tid >> 6, lane = tid & 63;
        int m = lane & 15, q = lane >> 4;
        int nbase = (blockIdx.x - GS) * 64 + wave * 16;
        int anode = nbase + m;
        bool rowok = anode < N;
        const float* xrow = x + (size_t)(rowok ? anode : 0) * 128 + q * 8;

        float4v acc[5];
        #pragma unroll
        for (int ct = 0; ct < 5; ct++)
            #pragma unroll
            for (int r = 0; r < 4; r++) acc[ct][r] = 0.f;

        #pragma unroll
        for (int kc = 0; kc < 4; kc++) {
            float4 u0 = make_float4(0.f, 0.f, 0.f, 0.f), u1 = u0;
            if (rowok) {
                u0 = *(const float4*)(xrow + kc * 32);
                u1 = *(const float4*)(xrow + kc * 32 + 4);
            }
            short8 af;
            af[0] = f2bf(u0.x); af[1] = f2bf(u0.y); af[2] = f2bf(u0.z); af[3] = f2bf(u0.w);
            af[4] = f2bf(u1.x); af[5] = f2bf(u1.y); af[6] = f2bf(u1.z); af[7] = f2bf(u1.w);
            #pragma unroll
            for (int ct = 0; ct < 5; ct++) {
                short8 bf = *(const short8*)&wt[(ct * 16 + m) * 136 + kc * 32 + q * 8];
                acc[ct] = __builtin_amdgcn_mfma_f32_16x16x32_bf16(af, bf, acc[ct], 0, 0, 0);
            }
        }
        #pragma unroll
        for (int ct = 0; ct < 4; ct++) {
            #pragma unroll
            for (int r = 0; r < 4; r++) {
                int n = nbase + q * 4 + r;
                if (n < N) h1[(size_t)n * 64 + ct * 16 + m] = __float2half(acc[ct][r]);
            }
        }
        #pragma unroll
        for (int r = 0; r < 4; r++) {
            int n = nbase + q * 4 + r;
            if (n < N) {
                float v = acc[4][r];
                if (m < 4) a_src[n * 4 + m] = v;
                else if (m < 8) a_dst[n * 4 + (m - 4)] = v;
            }
        }
    }
}

// layer-1 edge-centric aggregation + fused gemm2. One block per 128-node
// half-bucket; LDS-atomic channel accumulators; self-loop in epilogue.
__global__ __launch_bounds__(256) void k_agg1b(const int* __restrict__ stage,
                                               const int* __restrict__ cursor,
                                               const float* __restrict__ a_src,
                                               const float* __restrict__ a_dst,
                                               const __half* __restrict__ h1,
                                               const float* __restrict__ bias,
                                               const float* __restrict__ W2,
                                               const float* __restrict__ att_src2,
                                               const float* __restrict__ att_dst2,
                                               __half* __restrict__ h2,
                                               float* __restrict__ a_src2,
                                               float* __restrict__ a_dst2, int N) {
    __shared__ float accS[128][64];     // 32 KB  (64 % 32 == 0: stagger fixes banks)
    __shared__ float denS[128][4];
    __shared__ float adstS[128][4];
    __shared__ int   elist[ELCAP];
    __shared__ int   ecntS;
    __shared__ float sW2[64 * 17];
    __shared__ float sAs[16], sAd[16];
    int tid = threadIdx.x;
    int b = blockIdx.x >> 1, half = blockIdx.x & 1;
    int n0 = (b << BSH) + (half << 7);
    int nn = N - n0; if (nn > 128) nn = 128; if (nn < 0) nn = 0;

    float4* az = (float4*)accS;
    for (int i = tid; i < 128 * 64 / 4; i += 256) az[i] = make_float4(0.f, 0.f, 0.f, 0.f);
    if (tid < 128) {
        *(float4*)&denS[tid][0] = make_float4(0.f, 0.f, 0.f, 0.f);
        *(float4*)&adstS[tid][0] = (tid < nn) ? ((const float4*)a_dst)[n0 + tid]
                                              : make_float4(0.f, 0.f, 0.f, 0.f);
    }
    for (int i = tid; i < 1024; i += 256) sW2[(i >> 4) * 17 + (i & 15)] = W2[i];
    if (tid < 16) { sAs[tid] = att_src2[tid]; sAd[tid] = att_dst2[tid]; }
    if (tid == 0) ecntS = 0;
    __syncthreads();

    // compact this half's edges into LDS (ballot-aggregated cursor)
    int ecnt = cursor[b]; if (ecnt > BCAP) ecnt = BCAP;
    const int* sbk = stage + b * BCAP;
    int lane = tid & 63;
    for (int i0 = 0; i0 < ecnt; i0 += 256) {
        int i = i0 + tid;
        int v = 0; bool m = false;
        if (i < ecnt) { v = sbk[i]; m = (((v >> 24) & 1) == half); }
        unsigned long long mk = __ballot(m);
        int cnt = __popcll(mk);
        int wb = 0;
        if (lane == 0 && cnt) wb = atomicAdd(&ecntS, cnt);
        wb = __shfl(wb, 0, 64);
        if (m) {
            int p = wb + __popcll(mk & ((1ull << lane) - 1));
            if (p < ELCAP) elist[p] = v;
        }
    }
    __syncthreads();
    int EL = ecntS; if (EL > ELCAP) EL = ELCAP;

    // edge phase: 4 edges/wave-step, 16 lanes/edge (8B of the h1 row each)
    int wave = tid >> 6;
    int eoff = lane >> 4;          // 0..3 edge slot
    int c4 = lane & 15;            // channel quad
    int head = c4 >> 2;
    for (int base = wave * 4; base < EL; base += 16) {
        int e = base + eoff;
        bool val = e < EL;
        int v = elist[val ? e : 0];
        int s = v & 0x1FFFF;
        int dl = (v >> 17) & 127;
        float4 as4 = ((const float4*)a_src)[s];
        float am = head == 0 ? as4.x : head == 1 ? as4.y : head == 2 ? as4.z : as4.w;
        float xv = am + adstS[dl][head];
        float ea = __expf(fmaxf(xv, 0.2f * xv));
        union { float2 f; __half2 h[2]; } uu;
        uu.f = *(const float2*)&h1[(size_t)s * 64 + c4 * 4];
        float2 lo = __half22float2(uu.h[0]), hi = __half22float2(uu.h[1]);
        float vals[4] = {lo.x, lo.y, hi.x, hi.y};
        if (val) {
            #pragma unroll
            for (int k = 0; k < 4; k++) {
                int kk = (k + eoff) & 3;   // stagger: edges hit disjoint bank classes
                atomicAdd(&accS[dl][c4 * 4 + kk], ea * vals[kk]);
            }
            if ((c4 & 3) == 0) atomicAdd(&denS[dl][head], ea);
        }
    }
    __syncthreads();

    // epilogue: self-loop + normalize + ELU + fused gemm2 (8 lanes/node)
    int grp = lane >> 3, sub = lane & 3, par = (lane >> 2) & 1;
    for (int pass = 0; pass < 4; pass++) {
        int nl = pass * 32 + wave * 8 + grp;
        if (nl >= nn) continue;
        int node = n0 + nl;
        float asn = a_src[node * 4 + sub];
        float xs = asn + adstS[nl][sub];
        float es = __expf(fmaxf(xs, 0.2f * xs));
        float iv = 1.f / (denS[nl][sub] + es + 1e-16f);
        const _Float16* hbp = (const _Float16*)h1 + (size_t)node * 64 + sub * 16;
        half8 hp = *(const half8*)hbp;
        half8 hq = *(const half8*)(hbp + 8);
        const float4* bb = (const float4*)bias + sub * 4;
        float o[16];
        #pragma unroll
        for (int c = 0; c < 8; c++) {
            o[c]     = accS[nl][sub * 16 + c]     + es * (float)hp[c];
            o[c + 8] = accS[nl][sub * 16 + 8 + c] + es * (float)hq[c];
        }
        #pragma unroll
        for (int c4i = 0; c4i < 4; c4i++) {
            float4 bv = bb[c4i];
            float o0 = o[c4i * 4 + 0] * iv + bv.x;
            float o1 = o[c4i * 4 + 1] * iv + bv.y;
            float o2 = o[c4i * 4 + 2] * iv + bv.z;
            float o3 = o[c4i * 4 + 3] * iv + bv.w;
            o[c4i * 4 + 0] = (o0 > 0.f) ? o0 : (__expf(o0) - 1.f);
            o[c4i * 4 + 1] = (o1 > 0.f) ? o1 : (__expf(o1) - 1.f);
            o[c4i * 4 + 2] = (o2 > 0.f) ? o2 : (__expf(o2) - 1.f);
            o[c4i * 4 + 3] = (o3 > 0.f) ? o3 : (__expf(o3) - 1.f);
        }
        float pk[8];
        #pragma unroll
        for (int kk = 0; kk < 8; kk++) pk[kk] = 0.f;
        #pragma unroll
        for (int cc = 0; cc < 16; cc++) {
            float ov = o[cc];
            const float* wr = &sW2[(sub * 16 + cc) * 17 + par * 8];
            #pragma unroll
            for (int kk = 0; kk < 8; kk++) pk[kk] += ov * wr[kk];
        }
        #pragma unroll
        for (int kk = 0; kk < 8; kk++) {
            pk[kk] += __shfl_xor(pk[kk], 1, 64);
            pk[kk] += __shfl_xor(pk[kk], 2, 64);
        }
        if (sub == 0) {
            union { __half2 hh[4]; float4 f; } u2;
            u2.hh[0] = __floats2half2_rn(pk[0], pk[1]);
            u2.hh[1] = __floats2half2_rn(pk[2], pk[3]);
            u2.hh[2] = __floats2half2_rn(pk[4], pk[5]);
            u2.hh[3] = __floats2half2_rn(pk[6], pk[7]);
            *(float4*)&h2[(size_t)node * 16 + par * 8] = u2.f;
        }
        float ps = 0.f, pd = 0.f;
        #pragma unroll
        for (int kk = 0; kk < 8; kk++) {
            ps += pk[kk] * sAs[par * 8 + kk];
            pd += pk[kk] * sAd[par * 8 + kk];
        }
        ps += __shfl_xor(ps, 4, 64);
        pd += __shfl_xor(pd, 4, 64);
        if (sub == 0 && par == 0) { a_src2[node] = ps; a_dst2[node] = pd; }
    }
}

// layer-2 edge-centric aggregation + bias + log_softmax.
__global__ __launch_bounds__(256) void k_agg2b(const int* __restrict__ stage,
                                               const int* __restrict__ cursor,
                                               const float* __restrict__ a_src,
                                               const float* __restrict__ a_dst,
                                               const __half* __restrict__ h2,
                                               const float* __restrict__ bias,
                                               float* __restrict__ out, int N) {
    __shared__ float acc2S[128][17];    // padded: dl scrambles banks
    __shared__ float den2S[128];
    __shared__ float adstS2[128];
    __shared__ int   elist[ELCAP];
    __shared__ int   ecntS;
    __shared__ float biasS[16];
    int tid = threadIdx.x;
    int b = blockIdx.x >> 1, half = blockIdx.x & 1;
    int n0 = (b << BSH) + (half << 7);
    int nn = N - n0; if (nn > 128) nn = 128; if (nn < 0) nn = 0;

    for (int i = tid; i < 128 * 17; i += 256) ((float*)acc2S)[i] = 0.f;
    if (tid < 128) {
        den2S[tid] = 0.f;
        adstS2[tid] = (tid < nn) ? a_dst[n0 + tid] : 0.f;
    }
    if (tid < 16) biasS[tid] = bias[tid];
    if (tid == 0) ecntS = 0;
    __syncthreads();

    int ecnt = cursor[b]; if (ecnt > BCAP) ecnt = BCAP;
    const int* sbk = stage + b * BCAP;
    int lane = tid & 63;
    for (int i0 = 0; i0 < ecnt; i0 += 256) {
        int i = i0 + tid;
        int v = 0; bool m = false;
        if (i < ecnt) { v = sbk[i]; m = (((v >> 24) & 1) == half); }
        unsigned long long mk = __ballot(m);
        int cnt = __popcll(mk);
        int wb = 0;
        if (lane == 0 && cnt) wb = atomicAdd(&ecntS, cnt);
        wb = __shfl(wb, 0, 64);
        if (m) {
            int p = wb + __popcll(mk & ((1ull << lane) - 1));
            if (p < ELCAP) elist[p] = v;
        }
    }
    __syncthreads();
    int EL = ecntS; if (EL > ELCAP) EL = ELCAP;

    // edge phase: 8 edges/wave-step, 8 lanes/edge (4B of the h2 row each)
    int wave = tid >> 6;
    int eoff = lane >> 3;          // 0..7
    int ch2 = lane & 7;            // 2 channels
    for (int base = wave * 8; base < EL; base += 32) {
        int e = base + eoff;
        bool val = e < EL;
        int v = elist[val ? e : 0];
        int s = v & 0x1FFFF;
        int dl = (v >> 17) & 127;
        float a2 = a_src[s];
        float xv = a2 + adstS2[dl];
        float ea = __expf(fmaxf(xv, 0.2f * xv));
        float2 g = __half22float2(*(const __half2*)&h2[(size_t)s * 16 + ch2 * 2]);
        if (val) {
            atomicAdd(&acc2S[dl][ch2 * 2 + 0], ea * g.x);
            atomicAdd(&acc2S[dl][ch2 * 2 + 1], ea * g.y);
            if (ch2 == 0) atomicAdd(&den2S[dl], ea);
        }
    }
    __syncthreads();

    // epilogue: self-loop + normalize + bias + log_softmax (8 lanes/node)
    int grp = lane >> 3, sub = lane & 3, par = (lane >> 2) & 1;
    (void)par;
    for (int pass = 0; pass < 4; pass++) {
        int nl = pass * 32 + wave * 8 + grp;
        if (nl >= nn) continue;
        int node = n0 + nl;
        float a2n = a_src[node];
        float xs = a2n + adstS2[nl];
        float es = __expf(fmaxf(xs, 0.2f * xs));
        float iv = 1.f / (den2S[nl] + es + 1e-16f);
        union { float2 f; __half2 h[2]; } uu;
        uu.f = *(const float2*)&h2[(size_t)node * 16 + sub * 4];
        float2 lo = __half22float2(uu.h[0]), hi = __half22float2(uu.h[1]);
        float v0 = (acc2S[nl][sub * 4 + 0] + es * lo.x) * iv + biasS[sub * 4 + 0];
        float v1 = (acc2S[nl][sub * 4 + 1] + es * lo.y) * iv + biasS[sub * 4 + 1];
        float v2 = (acc2S[nl][sub * 4 + 2] + es * hi.x) * iv + biasS[sub * 4 + 2];
        float v3 = (acc2S[nl][sub * 4 + 3] + es * hi.y) * iv + biasS[sub * 4 + 3];
        float mx = fmaxf(fmaxf(v0, v1), fmaxf(v2, v3));
        mx = fmaxf(mx, __shfl_xor(mx, 1, 64));
        mx = fmaxf(mx, __shfl_xor(mx, 2, 64));
        float se = __expf(v0 - mx) + __expf(v1 - mx) + __expf(v2 - mx) + __expf(v3 - mx);
        se += __shfl_xor(se, 1, 64);
        se += __shfl_xor(se, 2, 64);
        float ls = mx + __logf(se);
        if (((lane >> 2) & 1) == 0)
            *(float4*)&out[(size_t)node * 16 + sub * 4] =
                make_float4(v0 - ls, v1 - ls, v2 - ls, v3 - ls);
    }
}

extern "C" void kernel_launch(void* const* d_in, const int* in_sizes, int n_in,
                              void* d_out, int out_size, void* d_ws, size_t ws_size,
                              hipStream_t stream) {
    const float* x        = (const float*)d_in[0];
    const int*   ei       = (const int*)d_in[1];
    const float* W1       = (const float*)d_in[2];
    const float* att_src1 = (const float*)d_in[3];
    const float* att_dst1 = (const float*)d_in[4];
    const float* bias1    = (const float*)d_in[5];
    const float* W2       = (const float*)d_in[6];
    const float* att_src2 = (const float*)d_in[7];
    const float* att_dst2 = (const float*)d_in[8];
    const float* bias2    = (const float*)d_in[9];
    float* out = (float*)d_out;

    const int N = in_sizes[0] / 128;
    const int E = in_sizes[1] / 2;
    const int NBK = (N + 255) >> BSH;
    const int GS = (E + CHK - 1) / CHK;
    const int GG = (N + 63) / 64;

    char* p = (char*)d_ws;
    auto alloc = [&](size_t bytes) -> void* {
        void* r = (void*)p;
        p += (bytes + 255) & ~(size_t)255;
        return r;
    };
    __half* h1     = (__half*)alloc((size_t)N * 64 * 2);
    __half* h2     = (__half*)alloc((size_t)N * 16 * 2);
    float* a_src1  = (float*)alloc((size_t)N * 4 * 4);
    float* a_dst1  = (float*)alloc((size_t)N * 4 * 4);
    float* a_src2  = (float*)alloc((size_t)N * 4);
    float* a_dst2  = (float*)alloc((size_t)N * 4);
    int*   stage   = (int*)alloc((size_t)NBK * BCAP * 4);
    int*   cursor  = (int*)alloc((size_t)NBK * 4);
    short* wtg     = (short*)alloc(80 * 136 * 2);
    (void)ws_size; (void)n_in; (void)out_size;

    k_init<<<2, 256, 0, stream>>>(cursor, NBK, W1, att_src1, att_dst1, wtg);
    k_pre<<<GS + GG, 256, 0, stream>>>(ei, cursor, stage, E, NBK,
                                       x, wtg, h1, a_src1, a_dst1, N, GS);
    k_agg1b<<<NBK * 2, 256, 0, stream>>>(stage, cursor, a_src1, a_dst1, h1, bias1,
                                         W2, att_src2, att_dst2,
                                         h2, a_src2, a_dst2, N);
    k_agg2b<<<NBK * 2, 256, 0, stream>>>(stage, cursor, a_src2, a_dst2, h2, bias2, out, N);
}

// Round 10
// 232.392 us; speedup vs baseline: 4.6972x; 4.6972x over previous
//
#include <hip/hip_runtime.h>
#include <hip/hip_fp16.h>
#include <hip/hip_bf16.h>
#include <math.h>

// GAT 2-layer forward, MI355X. FP32 in/out, int32 edge_index.
// R22: revert R21 (LDS float atomics = CAS loops, 757us). R19 pipeline with:
//  - k_init dropped: cursor via hipMemsetAsync; wtg fold inline in gemm1
//    blocks (R16-verified code). One fewer dispatch boundary.
//  - k_build2: half-bucket blocks (782): scan bucket stage, filter own half
//    via bit24 (R21-verified), histogram/fill 128 nodes. 2x parallelism in
//    the latency-bound build. int atomics only; csr writes bucket-local.
//  - k_agg1f / k_agg2: byte-identical R19 (measured at/near gather ceiling).
// memset + 4 kernels.

#define BSH 8            // 256 nodes per bucket
#define BCAP 5120        // staged capacity per bucket
#define CHK 4096         // edges per scatter block

typedef __attribute__((ext_vector_type(8))) short short8;
typedef __attribute__((ext_vector_type(8))) _Float16 half8;
typedef __attribute__((ext_vector_type(4))) _Float16 half4;
typedef __attribute__((ext_vector_type(4))) float float4v;

static __device__ __forceinline__ short f2bf(float f) {
    __hip_bfloat16 b = __float2bfloat16(f);
    return *reinterpret_cast<short*>(&b);
}

// Fused pass: blocks [0,GS) = edge scatter; blocks [GS,GS+GG) = gemm1.
__global__ __launch_bounds__(256) void k_pre(const int* __restrict__ ei, int* __restrict__ cursor,
                                             int* __restrict__ stage, int E, int NBK,
                                             const float* __restrict__ x,
                                             const float* __restrict__ W1,
                                             const float* __restrict__ att_src1,
                                             const float* __restrict__ att_dst1,
                                             __half* __restrict__ h1,
                                             float* __restrict__ a_src, float* __restrict__ a_dst,
                                             int N, int GS) {
    __shared__ __align__(16) char smem[80 * 136 * 2];   // 21760 B, union of roles
    int tid = threadIdx.x;
    if (blockIdx.x < GS) {
        // ---------------- scatter role (R19) ----------------
        int* hist = (int*)smem;          // [512]
        int* cnt2 = hist + 512;          // [512]
        int* base = cnt2 + 512;          // [512]
        int e0 = blockIdx.x * CHK;
        int nedge = E - e0; if (nedge > CHK) nedge = CHK;
        int nv4 = nedge >> 2, rem = nedge & 3;
        const int4* dv4 = (const int4*)(ei + E + e0);
        const int4* sv4 = (const int4*)(ei + e0);
        for (int i = tid; i < 512; i += 256) { hist[i] = 0; cnt2[i] = 0; }
        __syncthreads();
        for (int i = tid; i < nv4; i += 256) {
            int4 d = dv4[i];
            atomicAdd(&hist[d.x >> BSH], 1);
            atomicAdd(&hist[d.y >> BSH], 1);
            atomicAdd(&hist[d.z >> BSH], 1);
            atomicAdd(&hist[d.w >> BSH], 1);
        }
        if (tid < rem) atomicAdd(&hist[ei[E + e0 + nv4 * 4 + tid] >> BSH], 1);
        __syncthreads();
        for (int b = tid; b < NBK; b += 256) {
            int c = hist[b];
            if (c > 0) base[b] = b * BCAP + atomicAdd(&cursor[b], c);
        }
        __syncthreads();
        for (int i = tid; i < nv4; i += 256) {
            int4 s = sv4[i];
            int4 d = dv4[i];
            int b, r;
            b = d.x >> BSH; r = atomicAdd(&cnt2[b], 1);
            stage[base[b] + r] = s.x | ((d.x & 255) << 17);
            b = d.y >> BSH; r = atomicAdd(&cnt2[b], 1);
            stage[base[b] + r] = s.y | ((d.y & 255) << 17);
            b = d.z >> BSH; r = atomicAdd(&cnt2[b], 1);
            stage[base[b] + r] = s.z | ((d.z & 255) << 17);
            b = d.w >> BSH; r = atomicAdd(&cnt2[b], 1);
            stage[base[b] + r] = s.w | ((d.w & 255) << 17);
        }
        if (tid < rem) {
            int e = nv4 * 4 + tid;
            int s = ei[e0 + e];
            int d = ei[E + e0 + e];
            int b = d >> BSH;
            int r = atomicAdd(&cnt2[b], 1);
            stage[base[b] + r] = s | ((d & 255) << 17);
        }
    } else {
        // ---------------- gemm1 role (R16: inline fold) ----------------
        // h1[N,64](fp16) = x[N,128] @ W1[128,64] via MFMA 16x16x32 bf16.
        // cols 64-79 of B-tile: folded att1 columns (computed from W1).
        short* wt = (short*)smem;        // [80*136]
        for (int i = tid; i < 128 * 64; i += 256) {
            int k = i >> 6, c = i & 63;
            wt[c * 136 + k] = f2bf(W1[i]);
        }
        for (int i = tid; i < 16 * 128; i += 256) {
            int col = i >> 7, k = i & 127;
            float v = 0.f;
            if (col < 8) {
                int h = col & 3;
                const float* att = (col < 4) ? att_src1 : att_dst1;
                #pragma unroll
                for (int c = 0; c < 16; c++) v += W1[k * 64 + h * 16 + c] * att[h * 16 + c];
            }
            wt[(64 + col) * 136 + k] = f2bf(v);
        }
        __syncthreads();
        int wave = tid >> 6, lane = tid & 63;
        int m = lane & 15, q = lane >> 4;
        int nbase = (blockIdx.x - GS) * 64 + wave * 16;
        int anode = nbase + m;
        bool rowok = anode < N;
        const float* xrow = x + (size_t)(rowok ? anode : 0) * 128 + q * 8;

        float4v acc[5];
        #pragma unroll
        for (int ct = 0; ct < 5; ct++)
            #pragma unroll
            for (int r = 0; r < 4; r++) acc[ct][r] = 0.f;

        #pragma unroll
        for (int kc = 0; kc < 4; kc++) {
            float4 u0 = make_float4(0.f, 0.f, 0.f, 0.f), u1 = u0;
            if (rowok) {
                u0 = *(const float4*)(xrow + kc * 32);
                u1 = *(const float4*)(xrow + kc * 32 + 4);
            }
            short8 af;
            af[0] = f2bf(u0.x); af[1] = f2bf(u0.y); af[2] = f2bf(u0.z); af[3] = f2bf(u0.w);
            af[4] = f2bf(u1.x); af[5] = f2bf(u1.y); af[6] = f2bf(u1.z); af[7] = f2bf(u1.w);
            #pragma unroll
            for (int ct = 0; ct < 5; ct++) {
                short8 bf = *(const short8*)&wt[(ct * 16 + m) * 136 + kc * 32 + q * 8];
                acc[ct] = __builtin_amdgcn_mfma_f32_16x16x32_bf16(af, bf, acc[ct], 0, 0, 0);
            }
        }
        #pragma unroll
        for (int ct = 0; ct < 4; ct++) {
            #pragma unroll
            for (int r = 0; r < 4; r++) {
                int n = nbase + q * 4 + r;
                if (n < N) h1[(size_t)n * 64 + ct * 16 + m] = __float2half(acc[ct][r]);
            }
        }
        #pragma unroll
        for (int r = 0; r < 4; r++) {
            int n = nbase + q * 4 + r;
            if (n < N) {
                float v = acc[4][r];
                if (m < 4) a_src[n * 4 + m] = v;
                else if (m < 8) a_dst[n * 4 + (m - 4)] = v;
            }
        }
    }
}

// Half-bucket CSR build (R22): block = (bucket b, half). Scans the bucket's
// stage, keeps edges with local-node bit7 == half, histograms 128 nodes,
// scans, fills csr. Row offsets: gb = ebase + (half ? half0_edges : 0) + nodes0.
__global__ __launch_bounds__(256) void k_build2(const int* __restrict__ stage,
                                                const int* __restrict__ cursor,
                                                int* __restrict__ row_start,
                                                int* __restrict__ csr,
                                                int NBK, int E, int N) {
    __shared__ int cnt[128];
    __shared__ int lb[128];
    __shared__ int cur[128];
    __shared__ int sA[256];
    int blk = blockIdx.x, tid = threadIdx.x;
    int b = blk >> 1, half = blk & 1;
    int nodes0 = (b << BSH) + (half << 7);
    int nnodes = N - nodes0;
    if (nnodes > 128) nnodes = 128;
    if (nnodes < 0) nnodes = 0;
    // prefix of bucket edge counts
    int partial = 0;
    for (int i = tid; i < b; i += 256) partial += cursor[i];
    sA[tid] = partial;
    __syncthreads();
    for (int off = 128; off >= 1; off >>= 1) {
        if (tid < off) sA[tid] += sA[tid + off];
        __syncthreads();
    }
    int ebase = sA[0];
    int ecnt = cursor[b];
    __syncthreads();
    if (b == 0 && half == 0 && tid == 0) row_start[N] = E + N;
    const int* sbk = stage + b * BCAP;
    if (tid < 128) cnt[tid] = (tid < nnodes) ? 1 : 0;   // self loop
    __syncthreads();
    int hb = half << 7;
    int e4 = ecnt & ~3;
    for (int e = tid * 4; e < e4; e += 1024) {
        int4 v = *(const int4*)&sbk[e];
        int l;
        l = (v.x >> 17) & 255; if ((l & 128) == hb) atomicAdd(&cnt[l & 127], 1);
        l = (v.y >> 17) & 255; if ((l & 128) == hb) atomicAdd(&cnt[l & 127], 1);
        l = (v.z >> 17) & 255; if ((l & 128) == hb) atomicAdd(&cnt[l & 127], 1);
        l = (v.w >> 17) & 255; if ((l & 128) == hb) atomicAdd(&cnt[l & 127], 1);
    }
    if (tid < (ecnt & 3)) {
        int l = (sbk[e4 + tid] >> 17) & 255;
        if ((l & 128) == hb) atomicAdd(&cnt[l & 127], 1);
    }
    __syncthreads();
    // 128-wide inclusive scan of cnt (threads >=128 compute garbage harmlessly)
    int myc = (tid < 128) ? cnt[tid] : 0;
    sA[tid] = myc;
    __syncthreads();
    for (int off = 1; off < 128; off <<= 1) {
        int r = sA[tid] + ((tid >= off) ? sA[tid - off] : 0);
        __syncthreads();
        sA[tid] = r;
        __syncthreads();
    }
    int own_width = sA[127];                  // own edges + own self loops
    int own_edges = own_width - nnodes;
    int half0_edges = half ? (ecnt - own_edges) : 0;
    int gb = ebase + half0_edges + nodes0;
    if (tid < 128) {
        lb[tid] = sA[tid] - myc;
        cur[tid] = 1;
    }
    __syncthreads();
    if (tid < nnodes) {
        row_start[nodes0 + tid] = gb + lb[tid];
        csr[gb + lb[tid]] = nodes0 + tid;
    }
    __syncthreads();
    for (int e = tid * 4; e < e4; e += 1024) {
        int4 v = *(const int4*)&sbk[e];
        int l, r;
        l = (v.x >> 17) & 255;
        if ((l & 128) == hb) { r = atomicAdd(&cur[l & 127], 1); csr[gb + lb[l & 127] + r] = v.x & 0x1FFFF; }
        l = (v.y >> 17) & 255;
        if ((l & 128) == hb) { r = atomicAdd(&cur[l & 127], 1); csr[gb + lb[l & 127] + r] = v.y & 0x1FFFF; }
        l = (v.z >> 17) & 255;
        if ((l & 128) == hb) { r = atomicAdd(&cur[l & 127], 1); csr[gb + lb[l & 127] + r] = v.z & 0x1FFFF; }
        l = (v.w >> 17) & 255;
        if ((l & 128) == hb) { r = atomicAdd(&cur[l & 127], 1); csr[gb + lb[l & 127] + r] = v.w & 0x1FFFF; }
    }
    if (tid < (ecnt & 3)) {
        int v = sbk[e4 + tid];
        int l = (v >> 17) & 255;
        if ((l & 128) == hb) {
            int r = atomicAdd(&cur[l & 127], 1);
            csr[gb + lb[l & 127] + r] = v & 0x1FFFF;
        }
    }
}

// layer-1 aggregation with fused layer-2 GEMM epilogue (R19, unchanged).
// 8 nodes/wave, 8 lanes/node; csr pipelined; sW2 padded [64][17].
__global__ __launch_bounds__(256) void k_agg1f(const int* __restrict__ row_start,
                                               const int* __restrict__ csr_src,
                                               const float* __restrict__ a_src,
                                               const float* __restrict__ a_dst,
                                               const __half* __restrict__ h1,
                                               const float* __restrict__ bias,
                                               const float* __restrict__ W2,
                                               const float* __restrict__ att_src2,
                                               const float* __restrict__ att_dst2,
                                               __half* __restrict__ h2,
                                               float* __restrict__ a_src2,
                                               float* __restrict__ a_dst2, int N) {
    __shared__ float sW2[64 * 17];
    __shared__ float sAs[16], sAd[16];
    int tid = threadIdx.x;
    for (int i = tid; i < 1024; i += 256) sW2[(i >> 4) * 17 + (i & 15)] = W2[i];
    if (tid < 16) { sAs[tid] = att_src2[tid]; sAd[tid] = att_dst2[tid]; }
    __syncthreads();
    int wave = tid >> 6, lane = tid & 63;
    int grp = lane >> 3, sub = lane & 3, par = (lane >> 2) & 1;
    int node = blockIdx.x * 32 + wave * 8 + grp;
    if (node >= N) return;   // after the only barrier
    int row = row_start[node];
    int deg = row_start[node + 1] - row;
    float adm = a_dst[node * 4 + sub];
    const _Float16* hb = (const _Float16*)h1 + sub * 16;
    const int* cp = csr_src + row + par;
    float A[16];
    #pragma unroll
    for (int c = 0; c < 16; c++) A[c] = 0.f;
    float sh = 0.f;
    int c0 = 0, c1 = 0, c2 = 0, c3 = 0;
    if (deg >= 8) { c0 = cp[0]; c1 = cp[2]; c2 = cp[4]; c3 = cp[6]; }
    int j = 0;
    for (; j + 8 <= deg; j += 8) {
        int s0 = c0, s1 = c1, s2 = c2, s3 = c3;
        float x0 = a_src[s0 * 4 + sub] + adm;
        float x1 = a_src[s1 * 4 + sub] + adm;
        float x2 = a_src[s2 * 4 + sub] + adm;
        float x3 = a_src[s3 * 4 + sub] + adm;
        half8 p0 = *(const half8*)(hb + (size_t)s0 * 64);
        half8 q0 = *(const half8*)(hb + (size_t)s0 * 64 + 8);
        half8 p1 = *(const half8*)(hb + (size_t)s1 * 64);
        half8 q1 = *(const half8*)(hb + (size_t)s1 * 64 + 8);
        half8 p2 = *(const half8*)(hb + (size_t)s2 * 64);
        half8 q2 = *(const half8*)(hb + (size_t)s2 * 64 + 8);
        half8 p3 = *(const half8*)(hb + (size_t)s3 * 64);
        half8 q3 = *(const half8*)(hb + (size_t)s3 * 64 + 8);
        if (j + 16 <= deg) {
            c0 = cp[j + 8]; c1 = cp[j + 10]; c2 = cp[j + 12]; c3 = cp[j + 14];
        }
        float e0 = __expf(fmaxf(x0, 0.2f * x0));
        float e1 = __expf(fmaxf(x1, 0.2f * x1));
        float e2 = __expf(fmaxf(x2, 0.2f * x2));
        float e3 = __expf(fmaxf(x3, 0.2f * x3));
        sh += (e0 + e1) + (e2 + e3);
        #pragma unroll
        for (int c = 0; c < 8; c++) {
            A[c]     += e0 * (float)p0[c] + e1 * (float)p1[c]
                      + e2 * (float)p2[c] + e3 * (float)p3[c];
            A[c + 8] += e0 * (float)q0[c] + e1 * (float)q1[c]
                      + e2 * (float)q2[c] + e3 * (float)q3[c];
        }
    }
    for (; j < deg; j += 2) {
        int idx = j + par;
        if (idx < deg) {
            int s = csr_src[row + idx];
            float xv = a_src[s * 4 + sub] + adm;
            half8 p = *(const half8*)(hb + (size_t)s * 64);
            half8 q = *(const half8*)(hb + (size_t)s * 64 + 8);
            float e = __expf(fmaxf(xv, 0.2f * xv));
            sh += e;
            #pragma unroll
            for (int c = 0; c < 8; c++) {
                A[c]     += e * (float)p[c];
                A[c + 8] += e * (float)q[c];
            }
        }
    }
    sh += __shfl_xor(sh, 4, 64);
    #pragma unroll
    for (int c = 0; c < 16; c++) A[c] += __shfl_xor(A[c], 4, 64);
    float iv = 1.f / (sh + 1e-16f);
    const float4* bb = (const float4*)bias + sub * 4;
    float o[16];
    #pragma unroll
    for (int c4 = 0; c4 < 4; c4++) {
        float4 b = bb[c4];
        float o0 = A[c4 * 4 + 0] * iv + b.x;
        float o1 = A[c4 * 4 + 1] * iv + b.y;
        float o2 = A[c4 * 4 + 2] * iv + b.z;
        float o3 = A[c4 * 4 + 3] * iv + b.w;
        o[c4 * 4 + 0] = (o0 > 0.f) ? o0 : (__expf(o0) - 1.f);
        o[c4 * 4 + 1] = (o1 > 0.f) ? o1 : (__expf(o1) - 1.f);
        o[c4 * 4 + 2] = (o2 > 0.f) ? o2 : (__expf(o2) - 1.f);
        o[c4 * 4 + 3] = (o3 > 0.f) ? o3 : (__expf(o3) - 1.f);
    }
    // fused gemm2: pk[kk] = partial h2[par*8+kk] over this lane's 16 channels
    float pk[8];
    #pragma unroll
    for (int kk = 0; kk < 8; kk++) pk[kk] = 0.f;
    #pragma unroll
    for (int cc = 0; cc < 16; cc++) {
        float ov = o[cc];
        const float* wr = &sW2[(sub * 16 + cc) * 17 + par * 8];
        #pragma unroll
        for (int kk = 0; kk < 8; kk++) pk[kk] += ov * wr[kk];
    }
    #pragma unroll
    for (int kk = 0; kk < 8; kk++) {
        pk[kk] += __shfl_xor(pk[kk], 1, 64);
        pk[kk] += __shfl_xor(pk[kk], 2, 64);
    }
    if (sub == 0) {
        union { __half2 hh[4]; float4 f; } u;
        u.hh[0] = __floats2half2_rn(pk[0], pk[1]);
        u.hh[1] = __floats2half2_rn(pk[2], pk[3]);
        u.hh[2] = __floats2half2_rn(pk[4], pk[5]);
        u.hh[3] = __floats2half2_rn(pk[6], pk[7]);
        *(float4*)&h2[(size_t)node * 16 + par * 8] = u.f;
    }
    float ps = 0.f, pd = 0.f;
    #pragma unroll
    for (int kk = 0; kk < 8; kk++) {
        ps += pk[kk] * sAs[par * 8 + kk];
        pd += pk[kk] * sAd[par * 8 + kk];
    }
    ps += __shfl_xor(ps, 4, 64);
    pd += __shfl_xor(pd, 4, 64);
    if (sub == 0 && par == 0) { a_src2[node] = ps; a_dst2[node] = pd; }
}

// layer-2 aggregation + bias + log_softmax (R19, unchanged):
// 8 nodes/wave, 8 lanes/node (4 channel-quads x 2 parities), csr pipelined.
__global__ __launch_bounds__(256) void k_agg2(const int* __restrict__ row_start,
                                              const int* __restrict__ csr_src,
                                              const float* __restrict__ a_src,
                                              const float* __restrict__ a_dst,
                                              const __half* __restrict__ h2,
                                              const float* __restrict__ bias,
                                              float* __restrict__ out, int N) {
    int tid = threadIdx.x;
    int wave = tid >> 6, lane = tid & 63;
    int grp = lane >> 3, sub = lane & 3, par = (lane >> 2) & 1;
    int node = blockIdx.x * 32 + wave * 8 + grp;
    if (node >= N) return;
    int row = row_start[node];
    int deg = row_start[node + 1] - row;
    float ad = a_dst[node];
    const _Float16* hb = (const _Float16*)h2 + sub * 4;
    const int* cp = csr_src + row + par;
    float A0 = 0.f, A1 = 0.f, A2 = 0.f, A3 = 0.f;
    float sh = 0.f;
    int c0 = 0, c1 = 0, c2 = 0, c3 = 0;
    if (deg >= 8) { c0 = cp[0]; c1 = cp[2]; c2 = cp[4]; c3 = cp[6]; }
    int j = 0;
    for (; j + 8 <= deg; j += 8) {
        int s0 = c0, s1 = c1, s2 = c2, s3 = c3;
        float x0 = a_src[s0] + ad;
        float x1 = a_src[s1] + ad;
        float x2 = a_src[s2] + ad;
        float x3 = a_src[s3] + ad;
        half4 v0 = *(const half4*)(hb + (size_t)s0 * 16);
        half4 v1 = *(const half4*)(hb + (size_t)s1 * 16);
        half4 v2 = *(const half4*)(hb + (size_t)s2 * 16);
        half4 v3 = *(const half4*)(hb + (size_t)s3 * 16);
        if (j + 16 <= deg) {
            c0 = cp[j + 8]; c1 = cp[j + 10]; c2 = cp[j + 12]; c3 = cp[j + 14];
        }
        float e0 = __expf(fmaxf(x0, 0.2f * x0));
        float e1 = __expf(fmaxf(x1, 0.2f * x1));
        float e2 = __expf(fmaxf(x2, 0.2f * x2));
        float e3 = __expf(fmaxf(x3, 0.2f * x3));
        sh += (e0 + e1) + (e2 + e3);
        A0 += e0 * (float)v0[0] + e1 * (float)v1[0] + e2 * (float)v2[0] + e3 * (float)v3[0];
        A1 += e0 * (float)v0[1] + e1 * (float)v1[1] + e2 * (float)v2[1] + e3 * (float)v3[1];
        A2 += e0 * (float)v0[2] + e1 * (float)v1[2] + e2 * (float)v2[2] + e3 * (float)v3[2];
        A3 += e0 * (float)v0[3] + e1 * (float)v1[3] + e2 * (float)v2[3] + e3 * (float)v3[3];
    }
    for (; j < deg; j += 2) {
        int idx = j + par;
        if (idx < deg) {
            int s = csr_src[row + idx];
            float xv = a_src[s] + ad;
            half4 v = *(const half4*)(hb + (size_t)s * 16);
            float e = __expf(fmaxf(xv, 0.2f * xv));
            sh += e;
            A0 += e * (float)v[0];
            A1 += e * (float)v[1];
            A2 += e * (float)v[2];
            A3 += e * (float)v[3];
        }
    }
    sh += __shfl_xor(sh, 4, 64);
    A0 += __shfl_xor(A0, 4, 64);
    A1 += __shfl_xor(A1, 4, 64);
    A2 += __shfl_xor(A2, 4, 64);
    A3 += __shfl_xor(A3, 4, 64);
    float iv = 1.f / (sh + 1e-16f);
    float4 b = ((const float4*)bias)[sub];
    float v0 = A0 * iv + b.x;
    float v1 = A1 * iv + b.y;
    float v2 = A2 * iv + b.z;
    float v3 = A3 * iv + b.w;
    float mx = fmaxf(fmaxf(v0, v1), fmaxf(v2, v3));
    mx = fmaxf(mx, __shfl_xor(mx, 1, 64));
    mx = fmaxf(mx, __shfl_xor(mx, 2, 64));
    float se = __expf(v0 - mx) + __expf(v1 - mx) + __expf(v2 - mx) + __expf(v3 - mx);
    se += __shfl_xor(se, 1, 64);
    se += __shfl_xor(se, 2, 64);
    float ls = mx + __logf(se);
    if (par == 0)
        *(float4*)&out[(size_t)node * 16 + sub * 4] =
            make_float4(v0 - ls, v1 - ls, v2 - ls, v3 - ls);
}

extern "C" void kernel_launch(void* const* d_in, const int* in_sizes, int n_in,
                              void* d_out, int out_size, void* d_ws, size_t ws_size,
                              hipStream_t stream) {
    const float* x        = (const float*)d_in[0];
    const int*   ei       = (const int*)d_in[1];
    const float* W1       = (const float*)d_in[2];
    const float* att_src1 = (const float*)d_in[3];
    const float* att_dst1 = (const float*)d_in[4];
    const float* bias1    = (const float*)d_in[5];
    const float* W2       = (const float*)d_in[6];
    const float* att_src2 = (const float*)d_in[7];
    const float* att_dst2 = (const float*)d_in[8];
    const float* bias2    = (const float*)d_in[9];
    float* out = (float*)d_out;

    const int N = in_sizes[0] / 128;
    const int E = in_sizes[1] / 2;
    const int NBK = (N + 255) >> BSH;
    const int GS = (E + CHK - 1) / CHK;
    const int GG = (N + 63) / 64;

    char* p = (char*)d_ws;
    auto alloc = [&](size_t bytes) -> void* {
        void* r = (void*)p;
        p += (bytes + 255) & ~(size_t)255;
        return r;
    };
    __half* h1     = (__half*)alloc((size_t)N * 64 * 2);
    __half* h2     = (__half*)alloc((size_t)N * 16 * 2);
    float* a_src1  = (float*)alloc((size_t)N * 4 * 4);
    float* a_dst1  = (float*)alloc((size_t)N * 4 * 4);
    float* a_src2  = (float*)alloc((size_t)N * 4);
    float* a_dst2  = (float*)alloc((size_t)N * 4);
    int*   row_st  = (int*)alloc((size_t)(N + 1) * 4);
    int*   csr     = (int*)alloc((size_t)(E + N) * 4);
    int*   stage   = (int*)alloc((size_t)NBK * BCAP * 4);
    int*   cursor  = (int*)alloc((size_t)NBK * 4);
    (void)ws_size; (void)n_in; (void)out_size;

    hipMemsetAsync(cursor, 0, (size_t)NBK * 4, stream);
    k_pre<<<GS + GG, 256, 0, stream>>>(ei, cursor, stage, E, NBK,
                                       x, W1, att_src1, att_dst1,
                                       h1, a_src1, a_dst1, N, GS);
    k_build2<<<NBK * 2, 256, 0, stream>>>(stage, cursor, row_st, csr, NBK, E, N);
    k_agg1f<<<(N + 31) / 32, 256, 0, stream>>>(row_st, csr, a_src1, a_dst1, h1, bias1,
                                               W2, att_src2, att_dst2,
                                               h2, a_src2, a_dst2, N);
    k_agg2<<<(N + 31) / 32, 256, 0, stream>>>(row_st, csr, a_src2, a_dst2, h2, bias2, out, N);
}